// Round 1
// baseline (222.738 us; speedup 1.0000x reference)
//
#include <hip/hip_runtime.h>

#define DEV static __device__ __forceinline__

typedef float f32x4 __attribute__((ext_vector_type(4)));
typedef __bf16 bf16x8 __attribute__((ext_vector_type(8)));
typedef unsigned short u16x8 __attribute__((ext_vector_type(8)));

#define MFMA(a, b, c) __builtin_amdgcn_mfma_f32_16x16x32_bf16((a), (b), (c), 0, 0, 0)

// B=8, T=2048, C=1024, H=64
#define NB 8
#define TT 2048
#define CE 1024
#define HS 64

// ws layout (ushort elements)
#define WBT_E 0           // [3][64 n][1024 k] bf16 (Wq scaled by log2e/32)
#define Q_E   196608      // [B*T][64] bf16
#define K_E   (Q_E + 1048576)
#define V_E   (K_E + 1048576)
#define VT_E  (V_E + 1048576)   // [B][64 h][2048 t] bf16

DEV unsigned short cvt_bf16(float f) {
    unsigned int u = __builtin_bit_cast(unsigned int, f);
    u += 0x7FFFu + ((u >> 16) & 1u);   // round-to-nearest-even (finite inputs)
    return (unsigned short)(u >> 16);
}

DEV bf16x8 ld_bf8(const unsigned short* p) {
    union { u16x8 u; bf16x8 b; } v;
    v.u = *(const u16x8*)p;
    return v.b;
}

// ---------------- kernel 1: W fp32 -> bf16, transposed [n][k], Wq scaled ----
__global__ __launch_bounds__(256) void wconv_kernel(
        const float* __restrict__ Wq, const float* __restrict__ Wk,
        const float* __restrict__ Wv, unsigned short* __restrict__ wbt) {
    int id = blockIdx.x * 256 + threadIdx.x;      // < 3*64*1024
    int head = id >> 16;
    int rem = id & 65535;
    int n = rem >> 10;
    int k = rem & 1023;
    const float* W = (head == 0) ? Wq : ((head == 1) ? Wk : Wv);
    float v = W[k * HS + n];
    if (head == 0) v *= 0.045084220027780106f;    // log2(e)/32 folded into q
    wbt[id] = cvt_bf16(v);                        // wbt[head*65536 + n*1024 + k]
}

// ---------------- kernel 2: projection q,k,v = x @ W, plus v transposed -----
// grid 256 blocks (64 rows each), 256 threads (4 waves: wm=w&1 rows, wn=w>>1 cols)
__global__ __launch_bounds__(256) void proj_kernel(
        const float* __restrict__ x, const unsigned short* __restrict__ wbt,
        unsigned short* __restrict__ qws, unsigned short* __restrict__ kws,
        unsigned short* __restrict__ vws, unsigned short* __restrict__ vtws) {
    __shared__ __align__(16) unsigned short As[64 * 72];   // x tile [row][k], pad 72
    __shared__ __align__(16) unsigned short Ws[192 * 72];  // W tile [n][k], pad 72

    const int t = threadIdx.x;
    const int lane = t & 63, w = t >> 6;
    const int quad = lane >> 4, c = lane & 15;
    const int wm = w & 1, wn = w >> 1;
    const int t0 = blockIdx.x * 64;

    f32x4 acc[2][6] = {};

    for (int step = 0; step < 16; ++step) {
        const int ks = step * 64;
        __syncthreads();
        // stage A: 64x64 fp32 -> bf16 in LDS
        {
            int rbase = t >> 4, c4 = (t & 15) * 4;
            for (int i = 0; i < 4; ++i) {
                int row = rbase + i * 16;
                float4 f = *(const float4*)(x + (size_t)(t0 + row) * CE + ks + c4);
                unsigned long long pk =
                    (unsigned long long)cvt_bf16(f.x) |
                    ((unsigned long long)cvt_bf16(f.y) << 16) |
                    ((unsigned long long)cvt_bf16(f.z) << 32) |
                    ((unsigned long long)cvt_bf16(f.w) << 48);
                *(unsigned long long*)(&As[row * 72 + c4]) = pk;
            }
        }
        // stage W: 192 n-rows x 64 k, bf16 already, [n][k] layout
        for (int i = 0; i < 6; ++i) {
            int id = t + 256 * i;
            int n = id >> 3, cc = id & 7;
            u16x8 wc = *(const u16x8*)(wbt + n * 1024 + ks + cc * 8);
            *(u16x8*)(&Ws[n * 72 + cc * 8]) = wc;
        }
        __syncthreads();
        for (int kk = 0; kk < 2; ++kk) {
            bf16x8 a0 = ld_bf8(&As[(wm * 32 + c) * 72 + kk * 32 + quad * 8]);
            bf16x8 a1 = ld_bf8(&As[(wm * 32 + 16 + c) * 72 + kk * 32 + quad * 8]);
            for (int nt = 0; nt < 6; ++nt) {
                bf16x8 b = ld_bf8(&Ws[(wn * 96 + nt * 16 + c) * 72 + kk * 32 + quad * 8]);
                acc[0][nt] = MFMA(a0, b, acc[0][nt]);
                acc[1][nt] = MFMA(a1, b, acc[1][nt]);
            }
        }
    }

    __syncthreads();  // done with As as x-tile; reuse as Vt transpose buffer [h][t]
    for (int mt = 0; mt < 2; ++mt)
        for (int nt = 0; nt < 6; ++nt) {
            f32x4 a = acc[mt][nt];
            for (int r = 0; r < 4; ++r) {
                int rl = wm * 32 + mt * 16 + quad * 4 + r;
                int col = wn * 96 + nt * 16 + c;
                unsigned short hv = cvt_bf16(a[r]);
                size_t tg = (size_t)(t0 + rl);
                if (col < 64) {
                    qws[tg * HS + col] = hv;
                } else if (col < 128) {
                    kws[tg * HS + col - 64] = hv;
                } else {
                    vws[tg * HS + col - 128] = hv;
                    As[(col - 128) * 72 + rl] = hv;   // transpose via LDS
                }
            }
        }
    __syncthreads();
    // write vt [b][h][t] coalesced
    {
        int b = t0 >> 11, tl0 = t0 & 2047;
        int h = t >> 2;
        for (int i = 0; i < 2; ++i) {
            int cc2 = (t & 3) * 2 + i;
            u16x8 vc = *(const u16x8*)(&As[h * 72 + cc2 * 8]);
            *(u16x8*)(vtws + (size_t)(b * 64 + h) * TT + tl0 + cc2 * 8) = vc;
        }
    }
}

// ---------------- kernel 3: flash attention (causal + pad mask) -------------
// grid 256 blocks: b = blk>>5, qi = blk&31 (64 q-rows). 4 waves x 16 rows.
__global__ __launch_bounds__(256) void flash_kernel(
        const unsigned short* __restrict__ qws, const unsigned short* __restrict__ kws,
        const unsigned short* __restrict__ vtws, const int* __restrict__ pmask,
        float* __restrict__ out) {
    __shared__ __align__(16) unsigned short Ks[64 * 72];    // K tile [s][h]
    __shared__ __align__(16) unsigned short Vts[64 * 72];   // V tile [h][s]
    __shared__ __align__(16) unsigned short Ps[4 * 16 * 72];// per-wave P [m][s]
    __shared__ int pms[64];

    const int t = threadIdx.x;
    const int blk = blockIdx.x;
    const int b = blk >> 5, qi = blk & 31;
    const int t0 = qi * 64;
    const int lane = t & 63, w = t >> 6;
    const int quad = lane >> 4, c = lane & 15;
    const float NEGINF = -__builtin_inff();

    // Q fragments in registers (A-layout: m=lane&15, k=quad*8+j, kk selects 32-block)
    bf16x8 qf[2];
    for (int kk = 0; kk < 2; ++kk)
        qf[kk] = ld_bf8(qws + (size_t)(b * TT + t0 + w * 16 + c) * HS + kk * 32 + quad * 8);

    f32x4 o[4] = {};
    float m_run[4], l_run[4];
    for (int r = 0; r < 4; ++r) { m_run[r] = NEGINF; l_run[r] = 0.0f; }

    for (int j = 0; j <= qi; ++j) {
        __syncthreads();
        // stage K [s][h] and Vt [h][s] tiles (bf16, padded stride 72)
        for (int i = 0; i < 2; ++i) {
            int id = t + 256 * i;
            int row = id >> 3, cc = id & 7;
            *(u16x8*)(&Ks[row * 72 + cc * 8]) =
                *(const u16x8*)(kws + (size_t)(b * TT + j * 64 + row) * HS + cc * 8);
            *(u16x8*)(&Vts[row * 72 + cc * 8]) =
                *(const u16x8*)(vtws + (size_t)(b * 64 + row) * TT + j * 64 + cc * 8);
        }
        if (t < 64) pms[t] = pmask[b * TT + j * 64 + t];
        __syncthreads();

        // S = Q K^T  (scale & log2e folded into q)
        f32x4 s[4] = {};
        for (int kk = 0; kk < 2; ++kk)
            for (int nt = 0; nt < 4; ++nt) {
                bf16x8 bfr = ld_bf8(&Ks[(nt * 16 + c) * 72 + kk * 32 + quad * 8]);
                s[nt] = MFMA(qf[kk], bfr, s[nt]);
            }

        // masking
        int pm4[4];
        for (int nt = 0; nt < 4; ++nt) pm4[nt] = pms[nt * 16 + c];
        if (j == qi) {
            for (int nt = 0; nt < 4; ++nt) {
                int col = nt * 16 + c;
                for (int r = 0; r < 4; ++r) {
                    int rowl = w * 16 + quad * 4 + r;
                    if (pm4[nt] == 0 || col > rowl) s[nt][r] = NEGINF;
                }
            }
        } else {
            for (int nt = 0; nt < 4; ++nt)
                if (pm4[nt] == 0)
                    for (int r = 0; r < 4; ++r) s[nt][r] = NEGINF;
        }

        // online softmax (base-2 domain); rows live in 16-lane quad groups
        float al[4];
        for (int r = 0; r < 4; ++r) {
            float mx = fmaxf(fmaxf(s[0][r], s[1][r]), fmaxf(s[2][r], s[3][r]));
            mx = fmaxf(mx, __shfl_xor(mx, 1, 64));
            mx = fmaxf(mx, __shfl_xor(mx, 2, 64));
            mx = fmaxf(mx, __shfl_xor(mx, 4, 64));
            mx = fmaxf(mx, __shfl_xor(mx, 8, 64));
            float mnew = fmaxf(m_run[r], mx);
            al[r] = (mnew == NEGINF) ? 1.0f : exp2f(m_run[r] - mnew);
            m_run[r] = mnew;
        }
        for (int nt = 0; nt < 4; ++nt)
            for (int r = 0; r < 4; ++r)
                s[nt][r] = (s[nt][r] == NEGINF) ? 0.0f : exp2f(s[nt][r] - m_run[r]);
        for (int r = 0; r < 4; ++r) {
            float rs = s[0][r] + s[1][r] + s[2][r] + s[3][r];
            rs += __shfl_xor(rs, 1, 64);
            rs += __shfl_xor(rs, 2, 64);
            rs += __shfl_xor(rs, 4, 64);
            rs += __shfl_xor(rs, 8, 64);
            l_run[r] = l_run[r] * al[r] + rs;
        }
        for (int nt = 0; nt < 4; ++nt)
            for (int r = 0; r < 4; ++r) o[nt][r] *= al[r];

        // P: C-layout -> LDS -> A-layout (wave-private, no barrier needed)
        for (int nt = 0; nt < 4; ++nt)
            for (int r = 0; r < 4; ++r)
                Ps[w * 1152 + (quad * 4 + r) * 72 + nt * 16 + c] = cvt_bf16(s[nt][r]);

        // O += P V
        for (int kk = 0; kk < 2; ++kk) {
            bf16x8 pa = ld_bf8(&Ps[w * 1152 + c * 72 + kk * 32 + quad * 8]);
            for (int ht = 0; ht < 4; ++ht) {
                bf16x8 vb = ld_bf8(&Vts[(ht * 16 + c) * 72 + kk * 32 + quad * 8]);
                o[ht] = MFMA(pa, vb, o[ht]);
            }
        }
    }

    // epilogue: O / l
    float inv[4];
    for (int r = 0; r < 4; ++r) inv[r] = 1.0f / l_run[r];
    for (int nt = 0; nt < 4; ++nt)
        for (int r = 0; r < 4; ++r)
            out[(size_t)(b * TT + t0 + w * 16 + quad * 4 + r) * HS + nt * 16 + c] =
                o[nt][r] * inv[r];
}

extern "C" void kernel_launch(void* const* d_in, const int* in_sizes, int n_in,
                              void* d_out, int out_size, void* d_ws, size_t ws_size,
                              hipStream_t stream) {
    const float* x  = (const float*)d_in[0];
    const int* pm   = (const int*)d_in[1];
    const float* Wq = (const float*)d_in[2];
    const float* Wk = (const float*)d_in[3];
    const float* Wv = (const float*)d_in[4];
    float* out = (float*)d_out;

    unsigned short* wsu  = (unsigned short*)d_ws;
    unsigned short* wbt  = wsu + WBT_E;
    unsigned short* qws  = wsu + Q_E;
    unsigned short* kws  = wsu + K_E;
    unsigned short* vws  = wsu + V_E;
    unsigned short* vtws = wsu + VT_E;

    wconv_kernel<<<768, 256, 0, stream>>>(Wq, Wk, Wv, wbt);
    proj_kernel<<<256, 256, 0, stream>>>(x, wbt, qws, kws, vws, vtws);
    flash_kernel<<<256, 256, 0, stream>>>(qws, kws, vtws, pm, out);
}

// Round 3
// 174.624 us; speedup vs baseline: 1.2755x; 1.2755x over previous
//
#include <hip/hip_runtime.h>

#define DEV static __device__ __forceinline__

typedef float f32x4 __attribute__((ext_vector_type(4)));
typedef __bf16 bf16x8 __attribute__((ext_vector_type(8)));
typedef unsigned short u16x8 __attribute__((ext_vector_type(8)));

#define MFMA(a, b, c) __builtin_amdgcn_mfma_f32_16x16x32_bf16((a), (b), (c), 0, 0, 0)

// B=8, T=2048, C=1024, H=64
#define TT 2048
#define CE 1024
#define HS 64

// ws layout (ushort elements)
#define WBT_E 0                  // [3][64 n][1024 k] bf16 (Wq scaled by log2e/32)
#define Q_E   196608             // [B*T][64] bf16
#define K_E   (Q_E + 1048576)
#define VT_E  (K_E + 1048576)    // [B][64 h][2048 t] bf16

DEV unsigned short cvt_bf16(float f) {
    unsigned int u = __builtin_bit_cast(unsigned int, f);
    u += 0x7FFFu + ((u >> 16) & 1u);   // RNE (finite inputs)
    return (unsigned short)(u >> 16);
}

DEV bf16x8 ld_bf8(const unsigned short* p) {
    union { u16x8 u; bf16x8 b; } v;
    v.u = *(const u16x8*)p;
    return v.b;
}

// ---------------- kernel 1: W fp32 -> bf16 transposed [n][k], coalesced -----
// 48 blocks: head = blk>>4, ktile = blk&15 (64 k-rows each)
// Tr tile is 64 n x 64 k -> stride 72 (144B rows, 16B-mult). (Round-2 bug:
// stride 48 < 64 overlapped rows and ran OOB.)
__global__ __launch_bounds__(256) void wconv_kernel(
        const float* __restrict__ Wq, const float* __restrict__ Wk,
        const float* __restrict__ Wv, unsigned short* __restrict__ wbt) {
    __shared__ unsigned short Tr[64 * 72];
    const int blk = blockIdx.x;
    const int head = blk >> 4, kt = blk & 15;
    const int k0 = kt * 64;
    const float* W = (head == 0) ? Wq : ((head == 1) ? Wk : Wv);
    const float sc = (head == 0) ? 0.045084220027780106f : 1.0f;  // log2(e)/32
    const int t = threadIdx.x;
    const int rrow = t >> 4, c4 = (t & 15) * 4;
    for (int i = 0; i < 4; ++i) {
        int krow = rrow + i * 16;
        f32x4 f = *(const f32x4*)(W + (size_t)(k0 + krow) * 64 + c4);
        Tr[(c4 + 0) * 72 + krow] = cvt_bf16(f[0] * sc);
        Tr[(c4 + 1) * 72 + krow] = cvt_bf16(f[1] * sc);
        Tr[(c4 + 2) * 72 + krow] = cvt_bf16(f[2] * sc);
        Tr[(c4 + 3) * 72 + krow] = cvt_bf16(f[3] * sc);
    }
    __syncthreads();
    const int n = t >> 2, off = (t & 3) * 16;
    u16x8 a0 = *(const u16x8*)&Tr[n * 72 + off];
    u16x8 a1 = *(const u16x8*)&Tr[n * 72 + off + 8];
    unsigned short* dst = wbt + head * 65536 + n * 1024 + k0 + off;
    *(u16x8*)dst = a0;
    *(u16x8*)(dst + 8) = a1;
}

// ---------------- kernel 2: projection q,k = x@W; v transposed -> vt --------
// 512 blocks x 256 threads (4 waves). 32 rows/block, 192 cols.
// Double-buffered LDS + register prefetch: ONE barrier per k-step.
__global__ __launch_bounds__(256) void proj_kernel(
        const float* __restrict__ x, const unsigned short* __restrict__ wbt,
        unsigned short* __restrict__ qws, unsigned short* __restrict__ kws,
        unsigned short* __restrict__ vtws) {
    __shared__ __align__(16) unsigned short As[2 * 32 * 72];   // x tile [row][k]
    __shared__ __align__(16) unsigned short Ws[2 * 192 * 72];  // W tile [n][k]

    const int t = threadIdx.x;
    const int lane = t & 63, w = t >> 6;
    const int quad = lane >> 4, c = lane & 15;
    const int t0 = blockIdx.x * 32;
    const int xrow = t >> 3, xc = (t & 7) * 8;   // x staging: 8 thr/row

    f32x4 acc[2][3] = {};

    // prologue: stage step 0 into buffer 0
    {
        f32x4 f0 = *(const f32x4*)(x + (size_t)(t0 + xrow) * CE + xc);
        f32x4 f1 = *(const f32x4*)(x + (size_t)(t0 + xrow) * CE + xc + 4);
        u16x8 pk;
        for (int j = 0; j < 4; ++j) { pk[j] = cvt_bf16(f0[j]); pk[4 + j] = cvt_bf16(f1[j]); }
        *(u16x8*)&As[xrow * 72 + xc] = pk;
        for (int i = 0; i < 6; ++i) {
            int id = t + 256 * i, n = id >> 3, cc = id & 7;
            *(u16x8*)&Ws[n * 72 + cc * 8] = *(const u16x8*)(wbt + n * 1024 + cc * 8);
        }
    }
    __syncthreads();

    for (int step = 0; step < 16; ++step) {
        const int pb = step & 1, nb = pb ^ 1;
        const int ksn = ((step + 1) & 15) * 64;   // wraps on last step (discarded)
        // ---- issue prefetch loads for step+1 (latency overlaps compute) ----
        f32x4 f0 = *(const f32x4*)(x + (size_t)(t0 + xrow) * CE + ksn + xc);
        f32x4 f1 = *(const f32x4*)(x + (size_t)(t0 + xrow) * CE + ksn + xc + 4);
        u16x8 wv[6];
        for (int i = 0; i < 6; ++i) {
            int id = t + 256 * i, n = id >> 3, cc = id & 7;
            wv[i] = *(const u16x8*)(wbt + n * 1024 + ksn + cc * 8);
        }
        // ---- compute on current buffer ----
        for (int kk = 0; kk < 2; ++kk) {
            bf16x8 a0 = ld_bf8(&As[pb * 2304 + c * 72 + kk * 32 + quad * 8]);
            bf16x8 a1 = ld_bf8(&As[pb * 2304 + (16 + c) * 72 + kk * 32 + quad * 8]);
            for (int nt = 0; nt < 3; ++nt) {
                bf16x8 bb = ld_bf8(&Ws[pb * 13824 + (w * 48 + nt * 16 + c) * 72 + kk * 32 + quad * 8]);
                acc[0][nt] = MFMA(a0, bb, acc[0][nt]);
                acc[1][nt] = MFMA(a1, bb, acc[1][nt]);
            }
        }
        // ---- write prefetched data into other buffer ----
        {
            u16x8 pk;
            for (int j = 0; j < 4; ++j) { pk[j] = cvt_bf16(f0[j]); pk[4 + j] = cvt_bf16(f1[j]); }
            *(u16x8*)&As[nb * 2304 + xrow * 72 + xc] = pk;
            for (int i = 0; i < 6; ++i) {
                int id = t + 256 * i, n = id >> 3, cc = id & 7;
                *(u16x8*)&Ws[nb * 13824 + n * 72 + cc * 8] = wv[i];
            }
        }
        __syncthreads();
    }

    // epilogue: q,k direct; v transposed via LDS (reuse As, stride 48; tile
    // here is 64 h x 32 t so 48 > 32 is safe)
    unsigned short* TT2 = As;   // 64*48 = 3072 <= 4608 elems available
    for (int mt = 0; mt < 2; ++mt)
        for (int nt = 0; nt < 3; ++nt) {
            f32x4 a = acc[mt][nt];
            int col = w * 48 + nt * 16 + c;
            for (int r = 0; r < 4; ++r) {
                int row = mt * 16 + quad * 4 + r;
                size_t tg = (size_t)(t0 + row);
                unsigned short hv = cvt_bf16(a[r]);
                if (col < 64)       qws[tg * HS + col] = hv;
                else if (col < 128) kws[tg * HS + col - 64] = hv;
                else                TT2[(col - 128) * 48 + row] = hv;
            }
        }
    __syncthreads();
    {
        int h = t >> 2, off = (t & 3) * 8;
        u16x8 v = *(const u16x8*)&TT2[h * 48 + off];
        int b = t0 >> 11, tl0 = t0 & 2047;
        *(u16x8*)(vtws + (size_t)(b * 64 + h) * TT + tl0 + off) = v;
    }
}

// ---------------- kernel 3: flash attention, double-buffered ----------------
// 256 blocks: b=blk>>5, qi=blk&31. 4 waves x 16 q-rows. ONE barrier per iter.
// P-scratch lives in the INACTIVE V buffer (wave-aligned rows -> no hazard).
__global__ __launch_bounds__(256) void flash_kernel(
        const unsigned short* __restrict__ qws, const unsigned short* __restrict__ kws,
        const unsigned short* __restrict__ vtws, const int* __restrict__ pmask,
        float* __restrict__ out) {
    __shared__ __align__(16) unsigned short Ks[2 * 64 * 72];    // K tile [s][h]
    __shared__ __align__(16) unsigned short Vts[2 * 64 * 72];   // V^T tile [h][s]
    __shared__ int pms[2 * 64];

    const int t = threadIdx.x, blk = blockIdx.x;
    const int b = blk >> 5, qi = blk & 31;
    const int t0 = qi * 64;
    const int lane = t & 63, w = t >> 6;
    const int quad = lane >> 4, c = lane & 15;
    const float NEGINF = -__builtin_inff();

    // staging geometry
    const int krow0 = t >> 3, kcc = (t & 7) * 8;                 // K: rows krow0, krow0+32
    const int vrow0 = w * 16 + (lane >> 3), vcc = (lane & 7) * 8; // V: wave-aligned rows

    // Q fragments (A-layout: m=c, k=quad*8+j)
    bf16x8 qf[2];
    for (int kk = 0; kk < 2; ++kk)
        qf[kk] = ld_bf8(qws + (size_t)(b * TT + t0 + w * 16 + c) * HS + kk * 32 + quad * 8);

    // initial stage: tile 0 -> buffer 0
    u16x8 kr0 = *(const u16x8*)(kws + (size_t)(b * TT + krow0) * HS + kcc);
    u16x8 kr1 = *(const u16x8*)(kws + (size_t)(b * TT + krow0 + 32) * HS + kcc);
    u16x8 vr0 = *(const u16x8*)(vtws + (size_t)(b * 64 + vrow0) * TT + vcc);
    u16x8 vr1 = *(const u16x8*)(vtws + (size_t)(b * 64 + vrow0 + 8) * TT + vcc);
    int pr = (t < 64) ? pmask[b * TT + t] : 0;
    *(u16x8*)&Ks[krow0 * 72 + kcc] = kr0;
    *(u16x8*)&Ks[(krow0 + 32) * 72 + kcc] = kr1;
    *(u16x8*)&Vts[vrow0 * 72 + vcc] = vr0;
    *(u16x8*)&Vts[(vrow0 + 8) * 72 + vcc] = vr1;
    if (t < 64) pms[t] = pr;
    __syncthreads();

    f32x4 o[4] = {};
    float m_run[4], l_run[4];
    for (int r = 0; r < 4; ++r) { m_run[r] = NEGINF; l_run[r] = 0.0f; }

    for (int jj = 0; jj <= qi; ++jj) {
        const int pb = jj & 1, nb = pb ^ 1;
        const int jn = (jj < qi) ? jj + 1 : qi;   // last-iter loads discarded
        // ---- issue prefetch loads (overlap with compute below) ----
        kr0 = *(const u16x8*)(kws + (size_t)(b * TT + jn * 64 + krow0) * HS + kcc);
        kr1 = *(const u16x8*)(kws + (size_t)(b * TT + jn * 64 + krow0 + 32) * HS + kcc);
        vr0 = *(const u16x8*)(vtws + (size_t)(b * 64 + vrow0) * TT + jn * 64 + vcc);
        vr1 = *(const u16x8*)(vtws + (size_t)(b * 64 + vrow0 + 8) * TT + jn * 64 + vcc);
        pr = (t < 64) ? pmask[b * TT + jn * 64 + t] : 0;

        // ---- S = Q K^T (scale & log2e folded into q) ----
        f32x4 s4[4] = {};
        for (int kk = 0; kk < 2; ++kk)
            for (int nt = 0; nt < 4; ++nt) {
                bf16x8 bb = ld_bf8(&Ks[pb * 4608 + (nt * 16 + c) * 72 + kk * 32 + quad * 8]);
                s4[nt] = MFMA(qf[kk], bb, s4[nt]);
            }

        // ---- masking ----
        int pm4[4];
        for (int nt = 0; nt < 4; ++nt) pm4[nt] = pms[pb * 64 + nt * 16 + c];
        if (jj == qi) {
            for (int nt = 0; nt < 4; ++nt) {
                int col = nt * 16 + c;
                for (int r = 0; r < 4; ++r) {
                    int rowl = w * 16 + quad * 4 + r;
                    if (pm4[nt] == 0 || col > rowl) s4[nt][r] = NEGINF;
                }
            }
        } else {
            for (int nt = 0; nt < 4; ++nt)
                if (pm4[nt] == 0)
                    for (int r = 0; r < 4; ++r) s4[nt][r] = NEGINF;
        }

        // ---- online softmax (base-2), rows live in 16-lane groups ----
        float al[4];
        for (int r = 0; r < 4; ++r) {
            float mx = fmaxf(fmaxf(s4[0][r], s4[1][r]), fmaxf(s4[2][r], s4[3][r]));
            mx = fmaxf(mx, __shfl_xor(mx, 1, 64));
            mx = fmaxf(mx, __shfl_xor(mx, 2, 64));
            mx = fmaxf(mx, __shfl_xor(mx, 4, 64));
            mx = fmaxf(mx, __shfl_xor(mx, 8, 64));
            float mnew = fmaxf(m_run[r], mx);
            al[r] = (mnew == NEGINF) ? 1.0f : exp2f(m_run[r] - mnew);
            m_run[r] = mnew;
        }
        for (int nt = 0; nt < 4; ++nt)
            for (int r = 0; r < 4; ++r)
                s4[nt][r] = (s4[nt][r] == NEGINF) ? 0.0f : exp2f(s4[nt][r] - m_run[r]);
        for (int r = 0; r < 4; ++r) {
            float rs = s4[0][r] + s4[1][r] + s4[2][r] + s4[3][r];
            rs += __shfl_xor(rs, 1, 64);
            rs += __shfl_xor(rs, 2, 64);
            rs += __shfl_xor(rs, 4, 64);
            rs += __shfl_xor(rs, 8, 64);
            l_run[r] = l_run[r] * al[r] + rs;
        }
        for (int nt = 0; nt < 4; ++nt)
            for (int r = 0; r < 4; ++r) o[nt][r] *= al[r];

        // ---- P: C-layout -> LDS (in INACTIVE V buffer, own wave's rows) ----
        unsigned short* Psw = &Vts[nb * 4608 + (w * 16) * 72];
        for (int nt = 0; nt < 4; ++nt)
            for (int r = 0; r < 4; ++r)
                Psw[(quad * 4 + r) * 72 + nt * 16 + c] = cvt_bf16(s4[nt][r]);

        // ---- O += P V ----
        for (int kk = 0; kk < 2; ++kk) {
            bf16x8 pa = ld_bf8(&Psw[c * 72 + kk * 32 + quad * 8]);
            for (int ht = 0; ht < 4; ++ht) {
                bf16x8 vb = ld_bf8(&Vts[pb * 4608 + (ht * 16 + c) * 72 + kk * 32 + quad * 8]);
                o[ht] = MFMA(pa, vb, o[ht]);
            }
        }

        // ---- store prefetched tile into other buffer (overwrites Psw) ----
        *(u16x8*)&Ks[nb * 4608 + krow0 * 72 + kcc] = kr0;
        *(u16x8*)&Ks[nb * 4608 + (krow0 + 32) * 72 + kcc] = kr1;
        *(u16x8*)&Vts[nb * 4608 + vrow0 * 72 + vcc] = vr0;
        *(u16x8*)&Vts[nb * 4608 + (vrow0 + 8) * 72 + vcc] = vr1;
        if (t < 64) pms[nb * 64 + t] = pr;
        __syncthreads();
    }

    // epilogue: O / l
    float inv[4];
    for (int r = 0; r < 4; ++r) inv[r] = 1.0f / l_run[r];
    for (int nt = 0; nt < 4; ++nt)
        for (int r = 0; r < 4; ++r)
            out[(size_t)(b * TT + t0 + w * 16 + quad * 4 + r) * HS + nt * 16 + c] =
                o[nt][r] * inv[r];
}

extern "C" void kernel_launch(void* const* d_in, const int* in_sizes, int n_in,
                              void* d_out, int out_size, void* d_ws, size_t ws_size,
                              hipStream_t stream) {
    const float* x  = (const float*)d_in[0];
    const int* pm   = (const int*)d_in[1];
    const float* Wq = (const float*)d_in[2];
    const float* Wk = (const float*)d_in[3];
    const float* Wv = (const float*)d_in[4];
    float* out = (float*)d_out;

    unsigned short* wsu  = (unsigned short*)d_ws;
    unsigned short* wbt  = wsu + WBT_E;
    unsigned short* qws  = wsu + Q_E;
    unsigned short* kws  = wsu + K_E;
    unsigned short* vtws = wsu + VT_E;

    wconv_kernel<<<48, 256, 0, stream>>>(Wq, Wk, Wv, wbt);
    proj_kernel<<<512, 256, 0, stream>>>(x, wbt, qws, kws, vtws);
    flash_kernel<<<256, 256, 0, stream>>>(qws, kws, vtws, pm, out);
}